// Round 10
// baseline (229.802 us; speedup 1.0000x reference)
//
#include <hip/hip_runtime.h>

#define NX 160
#define NY 192
#define NZ 160
#define WIN 21
#define HALF 10
#define NTOT (NX * NY * NZ)     // 4,915,200
#define PLANE (NY * NZ)         // 30,720
#define NF 5
#define ROWF (NZ * NF)          // 800 floats per (x,y) row, field-interleaved
#define ROW4 (ROWF / 4)         // 200 float4 per row

// K1 (z-pass, register)
#define ZOUT 16
#define ZTH (NZ / ZOUT)         // 10 threads per row

// K2 (y-pass)
#define YCH 16                  // 12 chunks
#define YB_N (NX * ROW4 / 256)  // 125 blocks per chunk
#define YB_TOT (YB_N * (NY / YCH))  // 1500

// K3 (x-pass)
#define XC2 10                  // x-chunk; 16 chunks
#define XB_N (PLANE / 2 / 256)  // 60 col-blocks
#define XB_TOT (60 * (NX / XC2))    // 960

// bijective XCD-aware swizzle (m204 variant), nwg need not be %8
__device__ __forceinline__ int xcd_swz(int bid, int nwg) {
    const int q = nwg >> 3, r = nwg & 7;
    const int xcd = bid & 7, idx = bid >> 3;
    return (xcd < r ? xcd * (q + 1) : r * (q + 1) + (xcd - r) * q) + idx;
}

// ---------------------------------------------------------------------------
// K1: fused z-pass, pure-register, writes field-interleaved Bz.
// Thread: one (x,y) row, 16 consecutive z outputs. grid = 1200 x 256
// ---------------------------------------------------------------------------
__global__ __launch_bounds__(256) void k_zpass_i(const float* __restrict__ I,
                                                 const float* __restrict__ J,
                                                 float* __restrict__ Bz) {
    const int t = blockIdx.x * 256 + threadIdx.x;   // < 307200
    const int zc = t % ZTH;
    const int row = t / ZTH;                        // x*NY + y
    const int z0 = zc * ZOUT;
    const size_t rbase = (size_t)row * NZ;

    // window idx = z - z0 + 12; valid 2..37
    float aI[40], aJ[40];
#pragma unroll
    for (int k = 0; k < 10; ++k) {
        const int b = z0 - 12 + 4 * k;
        const int bc = b < 0 ? 0 : (b > NZ - 4 ? NZ - 4 : b);
        const float4 vI = *(const float4*)(I + rbase + bc);
        const float4 vJ = *(const float4*)(J + rbase + bc);
        const float m = (b == bc) ? 1.0f : 0.0f;
        aI[4*k+0] = m * vI.x; aI[4*k+1] = m * vI.y;
        aI[4*k+2] = m * vI.z; aI[4*k+3] = m * vI.w;
        aJ[4*k+0] = m * vJ.x; aJ[4*k+1] = m * vJ.y;
        aJ[4*k+2] = m * vJ.z; aJ[4*k+3] = m * vJ.w;
    }

    float s0 = 0.f, s1 = 0.f, s2 = 0.f, s3 = 0.f, s4 = 0.f;
#pragma unroll
    for (int d = 2; d <= 22; ++d) {
        const float a = aI[d], b = aJ[d];
        s0 += a; s1 += b;
        s2 = fmaf(a, a, s2); s3 = fmaf(b, b, s3); s4 = fmaf(a, b, s4);
    }

    float ob[5][4];
#pragma unroll
    for (int j = 0; j < ZOUT; ++j) {
        if (j > 0) {
            const float Aa = aI[j + 22], Ba = aJ[j + 22];
            const float Ar = aI[j + 1],  Br = aJ[j + 1];
            s0 += Aa - Ar;
            s1 += Ba - Br;
            s2 += Aa * Aa - Ar * Ar;
            s3 += Ba * Ba - Br * Br;
            s4 += Aa * Ba - Ar * Br;
        }
        const int e = j & 3;
        ob[0][e] = s0; ob[1][e] = s1; ob[2][e] = s2; ob[3][e] = s3; ob[4][e] = s4;
        if (e == 3) {
            const int zs = z0 + j - 3;                  // zs % 4 == 0
            float* op = Bz + (size_t)row * ROWF + (size_t)zs * NF;  // 16B aligned
            // 20 floats, flat i = zo*5+f -> ob[f][zo]
            ((float4*)op)[0] = make_float4(ob[0][0], ob[1][0], ob[2][0], ob[3][0]);
            ((float4*)op)[1] = make_float4(ob[4][0], ob[0][1], ob[1][1], ob[2][1]);
            ((float4*)op)[2] = make_float4(ob[3][1], ob[4][1], ob[0][2], ob[1][2]);
            ((float4*)op)[3] = make_float4(ob[2][2], ob[3][2], ob[4][2], ob[0][3]);
            ((float4*)op)[4] = make_float4(ob[1][3], ob[2][3], ob[3][3], ob[4][3]);
        }
    }
}

// ---------------------------------------------------------------------------
// K2: y-pass on interleaved layout = pure elementwise float4 running sum.
// Thread owns one float4 (z,f)-column of one x-slice; 3 contiguous streams.
// 1D grid 1500 blocks (XCD-swizzled), block 256
// ---------------------------------------------------------------------------
__global__ __launch_bounds__(256) void k_ypass_i(const float* __restrict__ Bz,
                                                 float* __restrict__ Bzy) {
    const int lid = xcd_swz(blockIdx.x, YB_TOT);
    const int ychunk = lid % (NY / YCH);
    const int tb = lid / (NY / YCH);
    const int t = tb * 256 + threadIdx.x;           // < 32000
    const int x = t / ROW4;
    const int c = t - x * ROW4;
    const int y0 = ychunk * YCH;

    const float4* src = (const float4*)Bz + (size_t)x * NY * ROW4 + c;
    float4* dst = (float4*)Bzy + (size_t)x * NY * ROW4 + c;

    float4 s = make_float4(0.f, 0.f, 0.f, 0.f);
#pragma unroll
    for (int k = -HALF; k <= HALF; ++k) {
        const int y = y0 + k;
        if (y >= 0 && y < NY) {
            const float4 v = src[(size_t)y * ROW4];
            s.x += v.x; s.y += v.y; s.z += v.z; s.w += v.w;
        }
    }
    for (int j = 0; j < YCH; ++j) {
        const int y = y0 + j;
        dst[(size_t)y * ROW4] = s;
        const int ya = y + HALF + 1;
        const int yr = y - HALF;
        if (ya < NY) {
            const float4 v = src[(size_t)ya * ROW4];
            s.x += v.x; s.y += v.y; s.z += v.z; s.w += v.w;
        }
        if (yr >= 0) {
            const float4 v = src[(size_t)yr * ROW4];
            s.x -= v.x; s.y -= v.y; s.z -= v.z; s.w -= v.w;
        }
    }
}

// ---------------------------------------------------------------------------
// K3: x-pass + cc + reduction on interleaved layout. Thread owns 2 voxels
// (zs, zs+1) of one (y,z) column; walks x with running sums; reads are
// float2x5 = 2 contiguous streams. 1D grid 960 blocks (XCD-swizzled).
// ---------------------------------------------------------------------------
__global__ __launch_bounds__(256) void k_xcc_i(const float* __restrict__ B,
                                               float* __restrict__ acc) {
    const int lid = xcd_swz(blockIdx.x, XB_TOT);
    const int xchunk = lid % (NX / XC2);
    const int cb = lid / (NX / XC2);
    const int cg = cb * 256 + threadIdx.x;          // < 15360
    const int y = cg / (NZ / 2);
    const int zs = (cg - y * (NZ / 2)) * 2;
    const int x0 = xchunk * XC2;

    const size_t colb = ((size_t)y * NZ + zs) * NF; // float offset within slice
    const size_t sstride = (size_t)PLANE * NF;      // per x-slice

    float a0=0.f,a1=0.f,a2=0.f,a3=0.f,a4=0.f;       // voxel zs sums
    float b0=0.f,b1=0.f,b2=0.f,b3=0.f,b4=0.f;       // voxel zs+1 sums

#pragma unroll
    for (int k = -HALF; k <= HALF; ++k) {
        const int xx = x0 + k;
        if (xx >= 0 && xx < NX) {
            const float2* p = (const float2*)(B + (size_t)xx * sstride + colb);
            const float2 L0=p[0], L1=p[1], L2=p[2], L3=p[3], L4=p[4];
            a0+=L0.x; a1+=L0.y; a2+=L1.x; a3+=L1.y; a4+=L2.x;
            b0+=L2.y; b1+=L3.x; b2+=L3.y; b3+=L4.x; b4+=L4.y;
        }
    }

    const float n = (float)(WIN * WIN * WIN);
    const float inv_n = 1.0f / n;
    float local = 0.0f;
    for (int j = 0; j < XC2; ++j) {
        const int x = x0 + j;
        {
            const float uI = a0 * inv_n, uJ = a1 * inv_n;
            const float cross = a4 - uJ * a0 - uI * a1 + uI * uJ * n;
            const float Ivar = a2 - 2.0f * uI * a0 + uI * uI * n;
            const float Jvar = a3 - 2.0f * uJ * a1 + uJ * uJ * n;
            local += cross * cross / (Ivar * Jvar + 1e-5f);
        }
        {
            const float uI = b0 * inv_n, uJ = b1 * inv_n;
            const float cross = b4 - uJ * b0 - uI * b1 + uI * uJ * n;
            const float Ivar = b2 - 2.0f * uI * b0 + uI * uI * n;
            const float Jvar = b3 - 2.0f * uJ * b1 + uJ * uJ * n;
            local += cross * cross / (Ivar * Jvar + 1e-5f);
        }
        const int xa = x + HALF + 1;
        const int xr = x - HALF;
        if (xa < NX) {
            const float2* p = (const float2*)(B + (size_t)xa * sstride + colb);
            const float2 L0=p[0], L1=p[1], L2=p[2], L3=p[3], L4=p[4];
            a0+=L0.x; a1+=L0.y; a2+=L1.x; a3+=L1.y; a4+=L2.x;
            b0+=L2.y; b1+=L3.x; b2+=L3.y; b3+=L4.x; b4+=L4.y;
        }
        if (xr >= 0) {
            const float2* p = (const float2*)(B + (size_t)xr * sstride + colb);
            const float2 L0=p[0], L1=p[1], L2=p[2], L3=p[3], L4=p[4];
            a0-=L0.x; a1-=L0.y; a2-=L1.x; a3-=L1.y; a4-=L2.x;
            b0-=L2.y; b1-=L3.x; b2-=L3.y; b3-=L4.x; b4-=L4.y;
        }
    }

    const int lane = threadIdx.x & 63;
    const int wid = threadIdx.x >> 6;
    for (int off = 32; off; off >>= 1) local += __shfl_down(local, off);
    __shared__ float red[4];
    if (lane == 0) red[wid] = local;
    __syncthreads();
    if (threadIdx.x == 0) {
        atomicAdd(acc, red[0] + red[1] + red[2] + red[3]);
    }
}

__global__ void finalize_k(const float* __restrict__ acc, float* __restrict__ out) {
    out[0] = 1.0f - acc[0] / (float)NTOT;
}

extern "C" void kernel_launch(void* const* d_in, const int* in_sizes, int n_in,
                              void* d_out, int out_size, void* d_ws, size_t ws_size,
                              hipStream_t stream) {
    const float* I = (const float*)d_in[0];
    const float* J = (const float*)d_in[1];
    float* out = (float*)d_out;

    float* acc = (float*)d_ws;
    float* Bz = (float*)((char*)d_ws + 256);            // 5*NTOT interleaved
    float* Bzy = Bz + (size_t)NF * NTOT;                // 5*NTOT interleaved
    // R7 proved the two-buffer path runs on this harness (ws >= 196.6 MB).

    hipMemsetAsync(d_ws, 0, 256, stream);

    k_zpass_i<<<NX * NY * ZTH / 256, 256, 0, stream>>>(I, J, Bz);   // 1200
    k_ypass_i<<<YB_TOT, 256, 0, stream>>>(Bz, Bzy);                 // 1500
    k_xcc_i<<<XB_TOT, 256, 0, stream>>>(Bzy, acc);                  // 960
    finalize_k<<<1, 1, 0, stream>>>(acc, out);
}